// Round 2
// baseline (887.494 us; speedup 1.0000x reference)
//
#include <hip/hip_runtime.h>
#include <hip/hip_bf16.h>
#include <stdint.h>

#define N_NODES 50000
#define N_EDGES 100000
#define EMB 512
#define HE_PAD 544          // 522 feature cols padded to 544 (17*32)
#define KP 2112             // 512 + 512 + 544 + 544
#define BM 128
#define BK 32
#define NT (KP / BK)        // 66 K-steps

typedef __bf16 bf16_t;
typedef __bf16 bf16x8 __attribute__((ext_vector_type(8)));
typedef float f32x4 __attribute__((ext_vector_type(4)));

__device__ __forceinline__ void gload_lds16(const void* g, void* l) {
    __builtin_amdgcn_global_load_lds(
        (const __attribute__((address_space(1))) uint32_t*)g,
        (__attribute__((address_space(3))) uint32_t*)l, 16, 0, 0);
}

__device__ __forceinline__ int swz4(int r) { return (r & 3) ^ ((r >> 2) & 3); }

// ---------------- PE-conv (DDE) kernels ----------------

__global__ void ret_scatter1(const int* __restrict__ ei, const float* __restrict__ topic,
                             float* deg_dst, float* deg_src, float* r1, float* s1) {
    int e = blockIdx.x * 256 + threadIdx.x;
    if (e >= N_EDGES) return;
    int s = ei[e], d = ei[N_EDGES + e];
    atomicAdd(&deg_dst[d], 1.f);
    atomicAdd(&deg_src[s], 1.f);
    atomicAdd(&r1[2 * d],     topic[2 * s]);
    atomicAdd(&r1[2 * d + 1], topic[2 * s + 1]);
    atomicAdd(&s1[2 * s],     topic[2 * d]);
    atomicAdd(&s1[2 * s + 1], topic[2 * d + 1]);
}

__global__ void ret_scatter2(const int* __restrict__ ei, const float* __restrict__ r1,
                             const float* __restrict__ s1, float* r2, float* s2) {
    int e = blockIdx.x * 256 + threadIdx.x;
    if (e >= N_EDGES) return;
    int s = ei[e], d = ei[N_EDGES + e];
    atomicAdd(&r2[2 * d],     r1[2 * s]);
    atomicAdd(&r2[2 * d + 1], r1[2 * s + 1]);
    atomicAdd(&s2[2 * s],     s1[2 * d]);
    atomicAdd(&s2[2 * s + 1], s1[2 * d + 1]);
}

__global__ void ret_norm(float* a, float* b, const float* deg_a, const float* deg_b) {
    int i = blockIdx.x * 256 + threadIdx.x;
    if (i >= N_NODES) return;
    float da = fmaxf(deg_a[i], 1.f);
    float db = fmaxf(deg_b[i], 1.f);
    a[2 * i]     /= da;
    a[2 * i + 1] /= da;
    b[2 * i]     /= db;
    b[2 * i + 1] /= db;
}

// ---------------- h_e assembly: [N][544] bf16 ----------------
// cols 0..511 = x (or ne_emb if all-zero row), 512..513 topic, 514..515 r1,
// 516..517 r2, 518..519 s1, 520..521 s2, 522..543 zero pad.

__global__ void ret_build_he(const float* __restrict__ x, const float* __restrict__ topic,
                             const float* __restrict__ r1, const float* __restrict__ r2,
                             const float* __restrict__ s1, const float* __restrict__ s2,
                             const float* __restrict__ ne, bf16_t* __restrict__ he) {
    int row = blockIdx.x * 4 + (threadIdx.x >> 6);
    if (row >= N_NODES) return;
    int lane = threadIdx.x & 63;
    const float* xr = x + (size_t)row * EMB + lane * 8;
    f32x4 f0 = *(const f32x4*)xr;
    f32x4 f1 = *(const f32x4*)(xr + 4);
    int nz = (f0[0] == 0.f) && (f0[1] == 0.f) && (f0[2] == 0.f) && (f0[3] == 0.f) &&
             (f1[0] == 0.f) && (f1[1] == 0.f) && (f1[2] == 0.f) && (f1[3] == 0.f);
    if (__all(nz)) {   // wave-uniform: whole row is zero -> use ne_emb
        f0 = *(const f32x4*)(ne + lane * 8);
        f1 = *(const f32x4*)(ne + lane * 8 + 4);
    }
    bf16x8 v;
    v[0] = (bf16_t)f0[0]; v[1] = (bf16_t)f0[1]; v[2] = (bf16_t)f0[2]; v[3] = (bf16_t)f0[3];
    v[4] = (bf16_t)f1[0]; v[5] = (bf16_t)f1[1]; v[6] = (bf16_t)f1[2]; v[7] = (bf16_t)f1[3];
    *(bf16x8*)&he[(size_t)row * HE_PAD + lane * 8] = v;
    if (lane < 32) {
        int c = lane;
        float val = 0.f;
        if      (c < 2)  val = topic[row * 2 + c];
        else if (c < 4)  val = r1[row * 2 + (c - 2)];
        else if (c < 6)  val = r2[row * 2 + (c - 4)];
        else if (c < 8)  val = s1[row * 2 + (c - 6)];
        else if (c < 10) val = s2[row * 2 + (c - 8)];
        he[(size_t)row * HE_PAD + EMB + c] = (bf16_t)val;
    }
}

// ---------------- W1 permute+pad+transpose: [512][2112] bf16 ----------------
// K' order: q(512) | edge_attr(512) | h_src(522+22 pad) | h_dst(522+22 pad)

__device__ __forceinline__ int ret_map_k(int kp) {
    if (kp < 512)  return kp;                               // q_emb rows 0..511
    if (kp < 1024) return 1034 + (kp - 512);                // edge_attr rows
    if (kp < 1568) { int t = kp - 1024; return (t < 522) ? (512 + t)  : -1; }  // h_src
    { int t = kp - 1568; return (t < 522) ? (1546 + t) : -1; }                  // h_dst
}

__global__ void ret_build_w1t(const float* __restrict__ w1, bf16_t* __restrict__ w1t) {
    __shared__ float tile[64][65];
    int k0 = blockIdx.x * 64;
    int n0 = blockIdx.y * 64;
    int j = threadIdx.x & 63;
    int q = threadIdx.x >> 6;   // 0..3
#pragma unroll
    for (int p = 0; p < 16; ++p) {
        int i = p * 4 + q;
        int krow = ret_map_k(k0 + i);
        tile[i][j] = (krow >= 0) ? w1[(size_t)krow * EMB + n0 + j] : 0.f;
    }
    __syncthreads();
#pragma unroll
    for (int p = 0; p < 16; ++p) {
        int nl = p * 4 + q;
        w1t[(size_t)(n0 + nl) * KP + k0 + j] = (bf16_t)tile[j][nl];
    }
}

// ---------------- Fused GEMM: out[e] = W2.relu(feat_e @ W1 + b1) + b2 ----------------
// Block: 128 edges x 512 out-cols, 8 waves (2M x 4N), wave tile 64x128.
// A staged to LDS (f32->bf16 convert or bf16 gather), B via global_load_lds
// from pre-transposed W1t. XOR slot swizzle on both LDS tiles.

__global__ __launch_bounds__(512, 2) void ret_gemm(
    const float* __restrict__ qe, const float* __restrict__ ea,
    const int* __restrict__ ei, const bf16_t* __restrict__ he,
    const bf16_t* __restrict__ w1t, const float* __restrict__ b1,
    const float* __restrict__ w2, const float* __restrict__ b2,
    float* __restrict__ out) {
    __shared__ bf16_t Ab[2][BM * BK];      // 2 x 8 KB
    __shared__ bf16_t Bb[2][EMB * BK];     // 2 x 32 KB
    __shared__ int nsrc[BM];
    __shared__ int ndst[BM];
    __shared__ float red[BM][4];

    const int tid = threadIdx.x;
    const int lane = tid & 63;
    const int wid = tid >> 6;
    const int wm = wid >> 2;    // 0..1
    const int wn = wid & 3;     // 0..3
    const int e0 = blockIdx.x * BM;

    if (tid < BM) {
        int e = min(e0 + tid, N_EDGES - 1);
        nsrc[tid] = ei[e];
        ndst[tid] = ei[N_EDGES + e];
    }

    f32x4 acc[4][8];
#pragma unroll
    for (int mf = 0; mf < 4; ++mf)
#pragma unroll
        for (int nf = 0; nf < 8; ++nf)
            acc[mf][nf] = (f32x4){0.f, 0.f, 0.f, 0.f};

    const int row = tid >> 2;       // staging row 0..127
    const int slot = tid & 3;       // staging 16B slot
    const int psw = slot ^ swz4(row);
    const int eA = min(e0 + row, N_EDGES - 1);

    auto stage = [&](int buf, int kt) {
        const int k0 = kt * BK;
        // ---- A tile: 128 rows x 32 k (bf16) ----
        if (k0 < 1024) {
            const float* src = (k0 < 512)
                ? (qe + (size_t)eA * EMB + k0 + slot * 8)
                : (ea + (size_t)eA * EMB + (k0 - 512) + slot * 8);
            f32x4 f0 = *(const f32x4*)src;
            f32x4 f1 = *(const f32x4*)(src + 4);
            bf16x8 v;
            v[0] = (bf16_t)f0[0]; v[1] = (bf16_t)f0[1]; v[2] = (bf16_t)f0[2]; v[3] = (bf16_t)f0[3];
            v[4] = (bf16_t)f1[0]; v[5] = (bf16_t)f1[1]; v[6] = (bf16_t)f1[2]; v[7] = (bf16_t)f1[3];
            *(bf16x8*)&Ab[buf][row * BK + psw * 8] = v;
        } else {
            const int node = (k0 < 1568) ? nsrc[row] : ndst[row];
            const int koff = (k0 < 1568) ? (k0 - 1024) : (k0 - 1568);
            bf16x8 v = *(const bf16x8*)(he + (size_t)node * HE_PAD + koff + slot * 8);
            *(bf16x8*)&Ab[buf][row * BK + psw * 8] = v;
        }
        // ---- B tile: 512 n-rows x 32 k, k-contiguous rows of 64B ----
#pragma unroll
        for (int i = 0; i < 4; ++i) {
            const int grp = wid * 4 + i;              // 0..31, 16 n-rows each
            const int n = grp * 16 + (lane >> 2);
            const int p = lane & 3;
            const int s = p ^ swz4(n);                // pre-swizzled source slot
            gload_lds16(w1t + (size_t)n * KP + k0 + s * 8,
                        &Bb[buf][grp * 512 + lane * 8]);
        }
    };

    const int r15 = lane & 15;
    const int sl = lane >> 4;
    const int psr = sl ^ swz4(r15);

    auto compute = [&](int buf) {
        bf16x8 a[4], b[8];
#pragma unroll
        for (int mf = 0; mf < 4; ++mf)
            a[mf] = *(const bf16x8*)&Ab[buf][(wm * 64 + mf * 16 + r15) * BK + psr * 8];
#pragma unroll
        for (int nf = 0; nf < 8; ++nf)
            b[nf] = *(const bf16x8*)&Bb[buf][(wn * 128 + nf * 16 + r15) * BK + psr * 8];
#pragma unroll
        for (int mf = 0; mf < 4; ++mf)
#pragma unroll
            for (int nf = 0; nf < 8; ++nf)
                acc[mf][nf] = __builtin_amdgcn_mfma_f32_16x16x32_bf16(a[mf], b[nf], acc[mf][nf], 0, 0, 0);
    };

    __syncthreads();          // nsrc/ndst visible
    stage(0, 0);
    int cur = 0;
    for (int kt = 0; kt < NT; ++kt) {
        __syncthreads();      // staging of buf[cur] drained (vmcnt+lgkm before barrier)
        if (kt + 1 < NT) stage(cur ^ 1, kt + 1);
        compute(cur);
        cur ^= 1;
    }

    // ---- epilogue: fused second layer ----
    float b1c[8], w2c[8];
#pragma unroll
    for (int nf = 0; nf < 8; ++nf) {
        int c = wn * 128 + nf * 16 + r15;
        b1c[nf] = b1[c];
        w2c[nf] = w2[c];
    }
#pragma unroll
    for (int mf = 0; mf < 4; ++mf) {
#pragma unroll
        for (int i = 0; i < 4; ++i) {
            float s = 0.f;
#pragma unroll
            for (int nf = 0; nf < 8; ++nf) {
                float h = acc[mf][nf][i] + b1c[nf];
                s += fmaxf(h, 0.f) * w2c[nf];
            }
            s += __shfl_xor(s, 1);
            s += __shfl_xor(s, 2);
            s += __shfl_xor(s, 4);
            s += __shfl_xor(s, 8);
            if (r15 == 0) red[wm * 64 + mf * 16 + sl * 4 + i][wn] = s;
        }
    }
    __syncthreads();
    if (tid < BM) {
        int e = e0 + tid;
        if (e < N_EDGES)
            out[e] = b2[0] + red[tid][0] + red[tid][1] + red[tid][2] + red[tid][3];
    }
}

// ---------------- launch ----------------

extern "C" void kernel_launch(void* const* d_in, const int* in_sizes, int n_in,
                              void* d_out, int out_size, void* d_ws, size_t ws_size,
                              hipStream_t stream) {
    const float* x     = (const float*)d_in[0];
    const int*   ei    = (const int*)d_in[1];
    const float* ea    = (const float*)d_in[2];
    const float* topic = (const float*)d_in[3];
    const float* qe    = (const float*)d_in[4];
    const float* ne    = (const float*)d_in[5];
    const float* w1    = (const float*)d_in[6];
    const float* b1    = (const float*)d_in[7];
    const float* w2    = (const float*)d_in[8];
    const float* b2    = (const float*)d_in[9];
    float* out = (float*)d_out;

    char* base = (char*)d_ws;
    float* deg_dst = (float*)base;
    float* deg_src = deg_dst + N_NODES;
    float* r1 = deg_src + N_NODES;
    float* s1 = r1 + 2 * N_NODES;
    float* r2 = s1 + 2 * N_NODES;
    float* s2 = r2 + 2 * N_NODES;
    size_t zero_bytes = (size_t)10 * N_NODES * sizeof(float);   // 2.0 MB
    bf16_t* he  = (bf16_t*)(base + zero_bytes);                 // 54.4 MB
    bf16_t* w1t = (bf16_t*)(base + zero_bytes +
                            (size_t)N_NODES * HE_PAD * sizeof(bf16_t)); // 2.16 MB

    hipMemsetAsync(d_ws, 0, zero_bytes, stream);
    ret_scatter1<<<(N_EDGES + 255) / 256, 256, 0, stream>>>(ei, topic, deg_dst, deg_src, r1, s1);
    ret_norm<<<(N_NODES + 255) / 256, 256, 0, stream>>>(r1, s1, deg_dst, deg_src);
    ret_scatter2<<<(N_EDGES + 255) / 256, 256, 0, stream>>>(ei, r1, s1, r2, s2);
    ret_norm<<<(N_NODES + 255) / 256, 256, 0, stream>>>(r2, s2, deg_dst, deg_src);
    ret_build_he<<<(N_NODES + 3) / 4, 256, 0, stream>>>(x, topic, r1, r2, s1, s2, ne, he);
    ret_build_w1t<<<dim3(KP / 64, EMB / 64), 256, 0, stream>>>(w1, w1t);
    ret_gemm<<<(N_EDGES + BM - 1) / BM, 512, 0, stream>>>(qe, ea, ei, he, w1t, b1, w2, b2, out);
}